// Round 12
// baseline (122.060 us; speedup 1.0000x reference)
//
#include <hip/hip_runtime.h>

#define LOG2E 1.4426950408889634f

constexpr int Bsz = 4096, Ssz = 128, Isz = 64, MOTOR = 32;
constexpr int BT = 4, NT = 256, R = 2;   // 256 thr = 128 s x 2 row-groups; 2 rows/thread

// ---- prep: fold constants, pack T[quad][{a,b,w}][s] as float4 ----
// a = -sigma*log2e ; b = sigma*mu*log2e ; w = w*mask*erev (sign carries erev)
__global__ void ltc_prep(const float* __restrict__ w, const float* __restrict__ sigma,
                         const float* __restrict__ mu, const float* __restrict__ erev,
                         const float* __restrict__ smask,
                         const float* __restrict__ sw, const float* __restrict__ ssig,
                         const float* __restrict__ smu, const float* __restrict__ serev,
                         const float* __restrict__ ssmask,
                         float4* __restrict__ Tm, float4* __restrict__ Ts)
{
  int idx = blockIdx.x * blockDim.x + threadIdx.x;
  if (idx < 32 * Ssz) {                    // main: 32 j-quads x 128 s
    int q = idx >> 7, s = idx & 127;
    float4 a, b, wv;
    #pragma unroll
    for (int jj = 0; jj < 4; ++jj) {
      int e = (q * 4 + jj) * Ssz + s;
      float sg = sigma[e];
      (&a.x)[jj] = -sg * LOG2E;
      (&b.x)[jj] = sg * mu[e] * LOG2E;
      (&wv.x)[jj] = w[e] * smask[e] * erev[e];
    }
    Tm[(q * 3 + 0) * Ssz + s] = a;
    Tm[(q * 3 + 1) * Ssz + s] = b;
    Tm[(q * 3 + 2) * Ssz + s] = wv;
  } else if (idx < 32 * Ssz + 16 * Ssz) {  // sensory: 16 i-quads x 128 s
    int k = idx - 32 * Ssz;
    int q = k >> 7, s = k & 127;
    float4 a, b, wv;
    #pragma unroll
    for (int jj = 0; jj < 4; ++jj) {
      int e = (q * 4 + jj) * Ssz + s;
      float sg = ssig[e];
      (&a.x)[jj] = -sg * LOG2E;
      (&b.x)[jj] = sg * smu[e] * LOG2E;
      (&wv.x)[jj] = sw[e] * ssmask[e] * serev[e];
    }
    Ts[(q * 3 + 0) * Ssz + s] = a;
    Ts[(q * 3 + 1) * Ssz + s] = b;
    Ts[(q * 3 + 2) * Ssz + s] = wv;
  }
}

// 4 sigmoids with 2 rcp (pair trick): sig_i = t_other * rcp(t0*t1)
__device__ __forceinline__ void sig_quad(float4 a4, float4 b4, float4 w4, float4 vq,
                                         float& num, float& den)
{
  float t0 = 1.0f + __builtin_amdgcn_exp2f(fmaf(a4.x, vq.x, b4.x));
  float t1 = 1.0f + __builtin_amdgcn_exp2f(fmaf(a4.y, vq.y, b4.y));
  float t2 = 1.0f + __builtin_amdgcn_exp2f(fmaf(a4.z, vq.z, b4.z));
  float t3 = 1.0f + __builtin_amdgcn_exp2f(fmaf(a4.w, vq.w, b4.w));
  float r01 = __builtin_amdgcn_rcpf(t0 * t1);
  float r23 = __builtin_amdgcn_rcpf(t2 * t3);
  float s0 = t1 * r01, s1 = t0 * r01;
  float s2 = t3 * r23, s3 = t2 * r23;
  num = fmaf(w4.x, s0, num); den = fmaf(fabsf(w4.x), s0, den);
  num = fmaf(w4.y, s1, num); den = fmaf(fabsf(w4.y), s1, den);
  num = fmaf(w4.z, s2, num); den = fmaf(fabsf(w4.z), s2, den);
  num = fmaf(w4.w, s3, num); den = fmaf(fabsf(w4.w), s3, den);
}

__launch_bounds__(NT, 4)   // cap 128 VGPR; live set ~60-90 with prefetch, no spill
__global__ void ltc_main(const float* __restrict__ inputs, const float* __restrict__ states,
                         const float* __restrict__ gleak, const float* __restrict__ vleak,
                         const float* __restrict__ cmv,
                         const float* __restrict__ iw, const float* __restrict__ ib,
                         const float* __restrict__ ow, const float* __restrict__ ob,
                         const float4* __restrict__ Tm, const float4* __restrict__ Ts,
                         float* __restrict__ out)
{
  __shared__ float vsh[2][BT][Ssz];   // double-buffered state: 4 KB
  __shared__ float xsh[BT][Isz];      // 1 KB

  const int t = threadIdx.x;
  const int s = t & 127;
  const int r0 = (t >> 7) * R;        // rows this thread owns
  const int b0 = blockIdx.x * BT;

  // stage x = inputs*iw + ib and v = states into LDS
  { int r = t >> 6, i = t & 63;
    xsh[r][i] = inputs[(b0 + r) * Isz + i] * iw[i] + ib[i]; }
  for (int k = t; k < BT * Ssz; k += NT) {
    int r = k >> 7, ss = k & 127;
    vsh[0][r][ss] = states[(b0 + r) * Ssz + ss];
  }
  const float cmt = cmv[s] * 6.0f;    // cm / (1.0/6)
  const float gl = gleak[s];
  const float gv = gl * vleak[s];
  const float dbase = cmt + gl + 1e-8f;
  __syncthreads();

  // ---- sensory sums: full i-range (16 quads), this thread's R rows ----
  float sn[R] = {0.f, 0.f}, sd[R] = {0.f, 0.f};
  {
    const float4* pb = Ts + 1 * Ssz + s;       // b-plane of quad 0
    float4 a4 = pb[-Ssz], b4 = pb[0], w4 = pb[Ssz];
    #pragma unroll 2
    for (int q = 0; q < 15; ++q) {
      float4 an = pb[2 * Ssz], bn = pb[3 * Ssz], wn = pb[4 * Ssz];   // prefetch next
      pb += 3 * Ssz;
      #pragma unroll
      for (int r = 0; r < R; ++r) {
        float4 xq = *(const float4*)&xsh[r0 + r][q * 4];   // broadcast read
        sig_quad(a4, b4, w4, xq, sn[r], sd[r]);
      }
      a4 = an; b4 = bn; w4 = wn;
    }
    #pragma unroll
    for (int r = 0; r < R; ++r) {                          // peeled last quad
      float4 xq = *(const float4*)&xsh[r0 + r][15 * 4];
      sig_quad(a4, b4, w4, xq, sn[r], sd[r]);
    }
  }

  // ---- 6 ODE unfolds: full j-sum per thread, 1 barrier per unfold ----
  #pragma unroll 1
  for (int it = 0; it < 6; ++it) {
    const int cur = it & 1;
    const float* vcur = &vsh[cur][0][0];
    float num[R], den[R];
    #pragma unroll
    for (int r = 0; r < R; ++r) { num[r] = sn[r]; den[r] = sd[r]; }

    const float4* pb = Tm + 1 * Ssz + s;       // b-plane of quad 0
    float4 a4 = pb[-Ssz], b4 = pb[0], w4 = pb[Ssz];
    #pragma unroll 2
    for (int q = 0; q < 31; ++q) {
      float4 an = pb[2 * Ssz], bn = pb[3 * Ssz], wn = pb[4 * Ssz];   // prefetch next
      pb += 3 * Ssz;
      #pragma unroll
      for (int r = 0; r < R; ++r) {
        float4 vq = *(const float4*)&vcur[(r0 + r) * Ssz + q * 4];   // broadcast read
        sig_quad(a4, b4, w4, vq, num[r], den[r]);
      }
      a4 = an; b4 = bn; w4 = wn;
    }
    #pragma unroll
    for (int r = 0; r < R; ++r) {                          // peeled last quad
      float4 vq = *(const float4*)&vcur[(r0 + r) * Ssz + 31 * 4];
      sig_quad(a4, b4, w4, vq, num[r], den[r]);
    }

    #pragma unroll
    for (int r = 0; r < R; ++r) {
      float vo = vcur[(r0 + r) * Ssz + s];
      vsh[cur ^ 1][r0 + r][s] =
          (fmaf(cmt, vo, gv) + num[r]) * __builtin_amdgcn_rcpf(dbase + den[r]);
    }
    __syncthreads();   // new buffer fully written & visible before next unfold reads it
  }

  // final state lives in vsh[0] (it=5 writes buffer 0)
  // ---- outputs: [B*32] motor affine, then [B*128] v_pre ----
  for (int k = t; k < BT * Ssz; k += NT) {
    int r = k >> 7, ss = k & 127;
    out[Bsz * MOTOR + (b0 + r) * Ssz + ss] = vsh[0][r][ss];
  }
  if (t < BT * MOTOR) {
    int r = t >> 5, m = t & 31;
    out[(b0 + r) * MOTOR + m] = fmaf(vsh[0][r][m], ow[m], ob[m]);
  }
}

extern "C" void kernel_launch(void* const* d_in, const int* in_sizes, int n_in,
                              void* d_out, int out_size, void* d_ws, size_t ws_size,
                              hipStream_t stream) {
  const float* inputs = (const float*)d_in[0];
  const float* states = (const float*)d_in[1];
  const float* gleak  = (const float*)d_in[2];
  const float* vleak  = (const float*)d_in[3];
  const float* cmv    = (const float*)d_in[4];
  const float* w      = (const float*)d_in[5];
  const float* sigma  = (const float*)d_in[6];
  const float* mu     = (const float*)d_in[7];
  const float* erev   = (const float*)d_in[8];
  const float* sw     = (const float*)d_in[9];
  const float* ssig   = (const float*)d_in[10];
  const float* smu    = (const float*)d_in[11];
  const float* serev  = (const float*)d_in[12];
  const float* smask  = (const float*)d_in[13];
  const float* ssmask = (const float*)d_in[14];
  const float* iw     = (const float*)d_in[15];
  const float* ib     = (const float*)d_in[16];
  const float* ow     = (const float*)d_in[17];
  const float* ob     = (const float*)d_in[18];

  char* ws = (char*)d_ws;
  float4* Tm = (float4*)ws;                  // 32 quads * 3 * 128 * 16B = 196608
  float4* Ts = (float4*)(ws + 196608);       // 16 quads * 3 * 128 * 16B =  98304
  float* out = (float*)d_out;

  constexpr int prep_items = 32 * Ssz + 16 * Ssz;   // 6144
  ltc_prep<<<(prep_items + 255) / 256, 256, 0, stream>>>(
      w, sigma, mu, erev, smask, sw, ssig, smu, serev, ssmask, Tm, Ts);
  ltc_main<<<Bsz / BT, NT, 0, stream>>>(
      inputs, states, gleak, vleak, cmv, iw, ib, ow, ob, Tm, Ts, out);
}

// Round 13
// 119.855 us; speedup vs baseline: 1.0184x; 1.0184x over previous
//
#include <hip/hip_runtime.h>

#define LOG2E 1.4426950408889634f

constexpr int Bsz = 4096, Ssz = 128, Isz = 64, MOTOR = 32;
constexpr int BT = 8, NT = 512, R = 2;   // 512 thr = 128 s x 4 row-groups; 2 rows/thread
constexpr int SMEM_BYTES = 65536 + 65536 + 8192 + 2048;   // A, B, vsh dbuf, xsh = 141312

// ---- prep: fold constants into separate planes ----
// Apl/Bpl/Wpl: [32][128] float4 (main); Asen/Bsen/Wsen: [16][128] float4 (sensory)
// a = -sigma*log2e ; b = sigma*mu*log2e ; w = w*mask*erev (sign carries erev)
__global__ void ltc_prep(const float* __restrict__ w, const float* __restrict__ sigma,
                         const float* __restrict__ mu, const float* __restrict__ erev,
                         const float* __restrict__ smask,
                         const float* __restrict__ sw, const float* __restrict__ ssig,
                         const float* __restrict__ smu, const float* __restrict__ serev,
                         const float* __restrict__ ssmask,
                         float4* __restrict__ Apl, float4* __restrict__ Bpl,
                         float4* __restrict__ Wpl,
                         float4* __restrict__ Asen, float4* __restrict__ Bsen,
                         float4* __restrict__ Wsen)
{
  int idx = blockIdx.x * blockDim.x + threadIdx.x;
  if (idx < 32 * Ssz) {                    // main: 32 j-quads x 128 s
    int q = idx >> 7, s = idx & 127;
    float4 a, b, wv;
    #pragma unroll
    for (int jj = 0; jj < 4; ++jj) {
      int e = (q * 4 + jj) * Ssz + s;
      float sg = sigma[e];
      (&a.x)[jj] = -sg * LOG2E;
      (&b.x)[jj] = sg * mu[e] * LOG2E;
      (&wv.x)[jj] = w[e] * smask[e] * erev[e];
    }
    Apl[idx] = a; Bpl[idx] = b; Wpl[idx] = wv;
  } else if (idx < 32 * Ssz + 16 * Ssz) {  // sensory: 16 i-quads x 128 s
    int k = idx - 32 * Ssz;
    int q = k >> 7, s = k & 127;
    float4 a, b, wv;
    #pragma unroll
    for (int jj = 0; jj < 4; ++jj) {
      int e = (q * 4 + jj) * Ssz + s;
      float sg = ssig[e];
      (&a.x)[jj] = -sg * LOG2E;
      (&b.x)[jj] = sg * smu[e] * LOG2E;
      (&wv.x)[jj] = sw[e] * ssmask[e] * serev[e];
    }
    Asen[k] = a; Bsen[k] = b; Wsen[k] = wv;
  }
}

__launch_bounds__(NT, 2)   // 256-VGPR ceiling: room for the scheduler to pipeline
__global__ void ltc_main(const float* __restrict__ inputs, const float* __restrict__ states,
                         const float* __restrict__ gleak, const float* __restrict__ vleak,
                         const float* __restrict__ cmv,
                         const float* __restrict__ iw, const float* __restrict__ ib,
                         const float* __restrict__ ow, const float* __restrict__ ob,
                         const float4* __restrict__ Apl, const float4* __restrict__ Bpl,
                         const float4* __restrict__ Wpl,
                         const float4* __restrict__ Asen, const float4* __restrict__ Bsen,
                         const float4* __restrict__ Wsen,
                         float* __restrict__ out)
{
  extern __shared__ char smem[];
  float4* Al = (float4*)smem;                       // [32][128] float4, 64 KB
  float4* Bl = (float4*)(smem + 65536);             // [32][128] float4, 64 KB
  float (*vsh)[BT][Ssz] = (float (*)[BT][Ssz])(smem + 131072);   // [2][8][128], 8 KB
  float (*xsh)[Isz] = (float (*)[Isz])(smem + 139264);           // [8][64], 2 KB

  const int t = threadIdx.x;
  const int s = t & 127;
  const int r0 = (t >> 7) * R;        // rows this thread owns
  const int b0 = blockIdx.x * BT;

  // ---- stage tables A,B into LDS (linear copy, coalesced) ----
  #pragma unroll
  for (int k = 0; k < 8; ++k) {
    Al[k * NT + t] = Apl[k * NT + t];
    Bl[k * NT + t] = Bpl[k * NT + t];
  }
  // stage x = inputs*iw + ib and v = states into LDS
  { int r = t >> 6, i = t & 63;       // 512 threads = 8 rows x 64 inputs exactly
    xsh[r][i] = inputs[(b0 + r) * Isz + i] * iw[i] + ib[i]; }
  #pragma unroll
  for (int k = 0; k < 2; ++k) {
    int kk = k * NT + t;
    int r = kk >> 7, ss = kk & 127;
    vsh[0][r][ss] = states[(b0 + r) * Ssz + ss];
  }
  const float cmt = cmv[s] * 6.0f;    // cm / (1.0/6)
  const float gl = gleak[s];
  const float gv = gl * vleak[s];
  const float dbase = cmt + gl + 1e-8f;
  __syncthreads();

  // ---- sensory sums: 16 i-quads from L2 (8% of work), indexed addressing ----
  float sn[R] = {0.f, 0.f}, sd[R] = {0.f, 0.f};
  #pragma unroll 4
  for (int q = 0; q < 16; ++q) {
    float4 a4 = Asen[q * Ssz + s];
    float4 b4 = Bsen[q * Ssz + s];
    float4 w4 = Wsen[q * Ssz + s];
    #pragma unroll
    for (int r = 0; r < R; ++r) {
      float4 xq = *(const float4*)&xsh[r0 + r][q * 4];   // broadcast read
      #pragma unroll
      for (int jj = 0; jj < 4; ++jj) {
        float arg = fmaf((&a4.x)[jj], (&xq.x)[jj], (&b4.x)[jj]);
        float u = __builtin_amdgcn_exp2f(arg);
        float sig = __builtin_amdgcn_rcpf(1.0f + u);
        sn[r] = fmaf((&w4.x)[jj], sig, sn[r]);
        sd[r] = fmaf(fabsf((&w4.x)[jj]), sig, sd[r]);
      }
    }
  }

  // ---- 6 ODE unfolds: A,B from LDS (imm offsets), W streamed from L2 ----
  #pragma unroll 1
  for (int it = 0; it < 6; ++it) {
    const int cur = it & 1;
    const float* vcur = &vsh[cur][0][0];
    float num[R], den[R];
    #pragma unroll
    for (int r = 0; r < R; ++r) { num[r] = sn[r]; den[r] = sd[r]; }

    #pragma unroll 4
    for (int q = 0; q < 32; ++q) {
      float4 w4 = Wpl[q * Ssz + s];        // L2, independent addresses
      float4 a4 = Al[q * Ssz + s];         // LDS, base + imm offset
      float4 b4 = Bl[q * Ssz + s];
      #pragma unroll
      for (int r = 0; r < R; ++r) {
        float4 vq = *(const float4*)&vcur[(r0 + r) * Ssz + q * 4];   // broadcast
        #pragma unroll
        for (int jj = 0; jj < 4; ++jj) {
          float arg = fmaf((&a4.x)[jj], (&vq.x)[jj], (&b4.x)[jj]);
          float u = __builtin_amdgcn_exp2f(arg);
          float sig = __builtin_amdgcn_rcpf(1.0f + u);
          num[r] = fmaf((&w4.x)[jj], sig, num[r]);
          den[r] = fmaf(fabsf((&w4.x)[jj]), sig, den[r]);
        }
      }
    }

    #pragma unroll
    for (int r = 0; r < R; ++r) {
      float vo = vcur[(r0 + r) * Ssz + s];
      vsh[cur ^ 1][r0 + r][s] =
          (fmaf(cmt, vo, gv) + num[r]) * __builtin_amdgcn_rcpf(dbase + den[r]);
    }
    __syncthreads();   // new buffer fully written & visible before next unfold
  }

  // final state lives in vsh[0] (it=5 writes buffer 0)
  // ---- outputs: [B*32] motor affine, then [B*128] v_pre ----
  #pragma unroll
  for (int k = 0; k < 2; ++k) {
    int kk = k * NT + t;
    int r = kk >> 7, ss = kk & 127;
    out[Bsz * MOTOR + (b0 + r) * Ssz + ss] = vsh[0][r][ss];
  }
  if (t < BT * MOTOR) {                // 256 threads = 8 rows x 32 motors
    int r = t >> 5, m = t & 31;
    out[(b0 + r) * MOTOR + m] = fmaf(vsh[0][r][m], ow[m], ob[m]);
  }
}

extern "C" void kernel_launch(void* const* d_in, const int* in_sizes, int n_in,
                              void* d_out, int out_size, void* d_ws, size_t ws_size,
                              hipStream_t stream) {
  const float* inputs = (const float*)d_in[0];
  const float* states = (const float*)d_in[1];
  const float* gleak  = (const float*)d_in[2];
  const float* vleak  = (const float*)d_in[3];
  const float* cmv    = (const float*)d_in[4];
  const float* w      = (const float*)d_in[5];
  const float* sigma  = (const float*)d_in[6];
  const float* mu     = (const float*)d_in[7];
  const float* erev   = (const float*)d_in[8];
  const float* sw     = (const float*)d_in[9];
  const float* ssig   = (const float*)d_in[10];
  const float* smu    = (const float*)d_in[11];
  const float* serev  = (const float*)d_in[12];
  const float* smask  = (const float*)d_in[13];
  const float* ssmask = (const float*)d_in[14];
  const float* iw     = (const float*)d_in[15];
  const float* ib     = (const float*)d_in[16];
  const float* ow     = (const float*)d_in[17];
  const float* ob     = (const float*)d_in[18];

  char* ws = (char*)d_ws;
  float4* Apl  = (float4*)ws;                  // 32*128*16 = 65536
  float4* Bpl  = (float4*)(ws + 65536);        // 65536
  float4* Wpl  = (float4*)(ws + 131072);       // 65536
  float4* Asen = (float4*)(ws + 196608);       // 16*128*16 = 32768
  float4* Bsen = (float4*)(ws + 229376);       // 32768
  float4* Wsen = (float4*)(ws + 262144);       // 32768  (total 294912 B)
  float* out = (float*)d_out;

  static_assert(SMEM_BYTES <= 160 * 1024, "LDS budget");
  hipFuncSetAttribute((const void*)ltc_main,
                      hipFuncAttributeMaxDynamicSharedMemorySize, SMEM_BYTES);

  constexpr int prep_items = 32 * Ssz + 16 * Ssz;   // 6144
  ltc_prep<<<(prep_items + 255) / 256, 256, 0, stream>>>(
      w, sigma, mu, erev, smask, sw, ssig, smu, serev, ssmask,
      Apl, Bpl, Wpl, Asen, Bsen, Wsen);
  ltc_main<<<Bsz / BT, NT, SMEM_BYTES, stream>>>(
      inputs, states, gleak, vleak, cmv, iw, ib, ow, ob,
      Apl, Bpl, Wpl, Asen, Bsen, Wsen, out);
}

// Round 14
// 113.693 us; speedup vs baseline: 1.0736x; 1.0542x over previous
//
#include <hip/hip_runtime.h>

#define LOG2E 1.4426950408889634f

constexpr int Bsz = 4096, Ssz = 128, Isz = 64, MOTOR = 32;
constexpr int BT = 4, NT = 256, R = 2;   // 256 thr = 128 s x 2 row-groups; 2 rows/thread

// ---- prep: fold constants, pack T[quad][{a,b,w}][s] as float4 ----
// a = -sigma*log2e ; b = sigma*mu*log2e ; w = w*mask*erev (sign carries erev)
__global__ void ltc_prep(const float* __restrict__ w, const float* __restrict__ sigma,
                         const float* __restrict__ mu, const float* __restrict__ erev,
                         const float* __restrict__ smask,
                         const float* __restrict__ sw, const float* __restrict__ ssig,
                         const float* __restrict__ smu, const float* __restrict__ serev,
                         const float* __restrict__ ssmask,
                         float4* __restrict__ Tm, float4* __restrict__ Ts)
{
  int idx = blockIdx.x * blockDim.x + threadIdx.x;
  if (idx < 32 * Ssz) {                    // main: 32 j-quads x 128 s
    int q = idx >> 7, s = idx & 127;
    float4 a, b, wv;
    #pragma unroll
    for (int jj = 0; jj < 4; ++jj) {
      int e = (q * 4 + jj) * Ssz + s;
      float sg = sigma[e];
      (&a.x)[jj] = -sg * LOG2E;
      (&b.x)[jj] = sg * mu[e] * LOG2E;
      (&wv.x)[jj] = w[e] * smask[e] * erev[e];
    }
    Tm[(q * 3 + 0) * Ssz + s] = a;
    Tm[(q * 3 + 1) * Ssz + s] = b;
    Tm[(q * 3 + 2) * Ssz + s] = wv;
  } else if (idx < 32 * Ssz + 16 * Ssz) {  // sensory: 16 i-quads x 128 s
    int k = idx - 32 * Ssz;
    int q = k >> 7, s = k & 127;
    float4 a, b, wv;
    #pragma unroll
    for (int jj = 0; jj < 4; ++jj) {
      int e = (q * 4 + jj) * Ssz + s;
      float sg = ssig[e];
      (&a.x)[jj] = -sg * LOG2E;
      (&b.x)[jj] = sg * smu[e] * LOG2E;
      (&wv.x)[jj] = sw[e] * ssmask[e] * serev[e];
    }
    Ts[(q * 3 + 0) * Ssz + s] = a;
    Ts[(q * 3 + 1) * Ssz + s] = b;
    Ts[(q * 3 + 2) * Ssz + s] = wv;
  }
}

__launch_bounds__(NT, 4)   // cap 128 VGPR; live set ~40, no spill
__global__ void ltc_main(const float* __restrict__ inputs, const float* __restrict__ states,
                         const float* __restrict__ gleak, const float* __restrict__ vleak,
                         const float* __restrict__ cmv,
                         const float* __restrict__ iw, const float* __restrict__ ib,
                         const float* __restrict__ ow, const float* __restrict__ ob,
                         const float4* __restrict__ Tm, const float4* __restrict__ Ts,
                         float* __restrict__ out)
{
  __shared__ float vsh[2][BT][Ssz];   // double-buffered state: 4 KB
  __shared__ float xsh[BT][Isz];      // 1 KB

  const int t = threadIdx.x;
  const int s = t & 127;
  const int r0 = (t >> 7) * R;        // rows this thread owns
  const int b0 = blockIdx.x * BT;

  // stage x = inputs*iw + ib and v = states into LDS
  { int r = t >> 6, i = t & 63;
    xsh[r][i] = inputs[(b0 + r) * Isz + i] * iw[i] + ib[i]; }
  for (int k = t; k < BT * Ssz; k += NT) {
    int r = k >> 7, ss = k & 127;
    vsh[0][r][ss] = states[(b0 + r) * Ssz + ss];
  }
  const float cmt = cmv[s] * 6.0f;    // cm / (1.0/6)
  const float gl = gleak[s];
  const float gv = gl * vleak[s];
  const float dbase = cmt + gl + 1e-8f;
  __syncthreads();

  // ---- sensory sums: full i-range (16 quads), this thread's R rows ----
  float sn[R] = {0.f, 0.f}, sd[R] = {0.f, 0.f};
  {
    const float4* pb = Ts + 1 * Ssz + s;       // points at b of quad 0
    #pragma unroll 2
    for (int q = 0; q < 16; ++q) {
      float4 a4 = pb[-Ssz], b4 = pb[0], w4 = pb[Ssz];
      pb += 3 * Ssz;
      #pragma unroll
      for (int r = 0; r < R; ++r) {
        float4 xq = *(const float4*)&xsh[r0 + r][q * 4];   // broadcast read
        #pragma unroll
        for (int jj = 0; jj < 4; ++jj) {
          float arg = fmaf((&a4.x)[jj], (&xq.x)[jj], (&b4.x)[jj]);
          float u = __builtin_amdgcn_exp2f(arg);
          float sig = __builtin_amdgcn_rcpf(1.0f + u);
          sn[r] = fmaf((&w4.x)[jj], sig, sn[r]);
          sd[r] = fmaf(fabsf((&w4.x)[jj]), sig, sd[r]);
        }
      }
    }
  }

  // ---- 6 ODE unfolds: full j-sum per thread, 1 barrier per unfold ----
  #pragma unroll 1
  for (int it = 0; it < 6; ++it) {
    const int cur = it & 1;
    const float* vcur = &vsh[cur][0][0];
    float num[R], den[R];
    #pragma unroll
    for (int r = 0; r < R; ++r) { num[r] = sn[r]; den[r] = sd[r]; }

    const float4* pb = Tm + 1 * Ssz + s;       // b of quad 0
    #pragma unroll 2
    for (int q = 0; q < 32; ++q) {
      float4 a4 = pb[-Ssz], b4 = pb[0], w4 = pb[Ssz];
      pb += 3 * Ssz;
      #pragma unroll
      for (int r = 0; r < R; ++r) {
        float4 vq = *(const float4*)&vcur[(r0 + r) * Ssz + q * 4];  // broadcast read
        #pragma unroll
        for (int jj = 0; jj < 4; ++jj) {
          float arg = fmaf((&a4.x)[jj], (&vq.x)[jj], (&b4.x)[jj]);
          float u = __builtin_amdgcn_exp2f(arg);
          float sig = __builtin_amdgcn_rcpf(1.0f + u);
          num[r] = fmaf((&w4.x)[jj], sig, num[r]);
          den[r] = fmaf(fabsf((&w4.x)[jj]), sig, den[r]);
        }
      }
    }

    #pragma unroll
    for (int r = 0; r < R; ++r) {
      float vo = vcur[(r0 + r) * Ssz + s];
      vsh[cur ^ 1][r0 + r][s] =
          (fmaf(cmt, vo, gv) + num[r]) * __builtin_amdgcn_rcpf(dbase + den[r]);
    }
    __syncthreads();   // new buffer fully written & visible before next unfold reads it
  }

  // final state lives in vsh[0] (it=5 writes buffer 0)
  // ---- outputs: [B*32] motor affine, then [B*128] v_pre ----
  for (int k = t; k < BT * Ssz; k += NT) {
    int r = k >> 7, ss = k & 127;
    out[Bsz * MOTOR + (b0 + r) * Ssz + ss] = vsh[0][r][ss];
  }
  if (t < BT * MOTOR) {
    int r = t >> 5, m = t & 31;
    out[(b0 + r) * MOTOR + m] = fmaf(vsh[0][r][m], ow[m], ob[m]);
  }
}

extern "C" void kernel_launch(void* const* d_in, const int* in_sizes, int n_in,
                              void* d_out, int out_size, void* d_ws, size_t ws_size,
                              hipStream_t stream) {
  const float* inputs = (const float*)d_in[0];
  const float* states = (const float*)d_in[1];
  const float* gleak  = (const float*)d_in[2];
  const float* vleak  = (const float*)d_in[3];
  const float* cmv    = (const float*)d_in[4];
  const float* w      = (const float*)d_in[5];
  const float* sigma  = (const float*)d_in[6];
  const float* mu     = (const float*)d_in[7];
  const float* erev   = (const float*)d_in[8];
  const float* sw     = (const float*)d_in[9];
  const float* ssig   = (const float*)d_in[10];
  const float* smu    = (const float*)d_in[11];
  const float* serev  = (const float*)d_in[12];
  const float* smask  = (const float*)d_in[13];
  const float* ssmask = (const float*)d_in[14];
  const float* iw     = (const float*)d_in[15];
  const float* ib     = (const float*)d_in[16];
  const float* ow     = (const float*)d_in[17];
  const float* ob     = (const float*)d_in[18];

  char* ws = (char*)d_ws;
  float4* Tm = (float4*)ws;                  // 32 quads * 3 * 128 * 16B = 196608
  float4* Ts = (float4*)(ws + 196608);       // 16 quads * 3 * 128 * 16B =  98304
  float* out = (float*)d_out;

  constexpr int prep_items = 32 * Ssz + 16 * Ssz;   // 6144
  ltc_prep<<<(prep_items + 255) / 256, 256, 0, stream>>>(
      w, sigma, mu, erev, smask, sw, ssig, smu, serev, ssmask, Tm, Ts);
  ltc_main<<<Bsz / BT, NT, 0, stream>>>(
      inputs, states, gleak, vleak, cmv, iw, ib, ow, ob, Tm, Ts, out);
}